// Round 19
// baseline (696.504 us; speedup 1.0000x reference)
//
// v9.1 — identical to v9 (r18); resubmit after UnresponsiveContainer.
#include <hip/hip_runtime.h>

#define B_  2
#define S_  2048
#define D_  2048
#define H_  16
#define DH_ 128
#define L_  512
#define M_  (B_*S_)

typedef unsigned short u16;
typedef float f32x4 __attribute__((ext_vector_type(4)));
typedef short short8 __attribute__((ext_vector_type(8)));
typedef u16 u16x4 __attribute__((ext_vector_type(4)));
typedef u16 u16x8 __attribute__((ext_vector_type(8)));

__device__ inline float bf2f(u16 u) {
    union { unsigned int i; float f; } x; x.i = ((unsigned int)u) << 16; return x.f;
}
__device__ inline u16 f2bf(float f) {
    union { float f; unsigned int i; } x; x.f = f;
    unsigned int r = x.i + 0x7FFFu + ((x.i >> 16) & 1u);
    return (u16)(r >> 16);
}
__device__ inline f32x4 mfma16(short8 a, short8 b, f32x4 c) {
    return __builtin_amdgcn_mfma_f32_16x16x32_bf16(a, b, c, 0, 0, 0);
}

typedef const __attribute__((address_space(1))) unsigned int gu32;
typedef __attribute__((address_space(3))) unsigned int lu32;
__device__ inline void gload16(const u16* g, u16* l) {
    __builtin_amdgcn_global_load_lds((gu32*)g, (lu32*)l, 16, 0, 0);
}

template <typename T> __device__ inline void store1(T* p, float v);
template <> __device__ inline void store1<float>(float* p, float v) { *p = v; }
template <> __device__ inline void store1<u16>(u16* p, float v) { *p = f2bf(v); }

// ---------------------------------------------------------------------------
// MFMA GEMM: C[M][N] = A[M][K] @ B[N][K]^T, A/B bf16, f32 accum, TC out.
// Templated tile BM x BN, 4 waves arranged WAVES_M x WAVES_N, BK=32,
// global_load_lds staging, k-slice LDS layout [ks][row][8] (conflict-free).
// grid = (N/BN, M/BM).
// ---------------------------------------------------------------------------
template <typename TC, int BM, int BN, int WAVES_M, int WAVES_N>
__global__ __launch_bounds__(256) void mgemm(const u16* __restrict__ A,
                                             const u16* __restrict__ Bm,
                                             TC* __restrict__ C,
                                             int N, int K) {
    constexpr int WM = BM / WAVES_M;
    constexpr int WN = BN / WAVES_N;
    constexpr int FM = WM / 16;
    constexpr int FN = WN / 16;
    constexpr int CA = (BM * 4) / 256;
    constexpr int CB = (BN * 4) / 256;

    const int tid = threadIdx.x;
    const int bn = blockIdx.x * BN, bm = blockIdx.y * BM;
    const int w = tid >> 6, l = tid & 63;
    const int wr = w / WAVES_N, wc = w % WAVES_N;
    const int g = l >> 4, ln16 = l & 15;

    __shared__ u16 A_lds[BM * 32];
    __shared__ u16 B_lds[BN * 32];

    f32x4 acc[FM][FN];
#pragma unroll
    for (int m = 0; m < FM; ++m)
#pragma unroll
        for (int n = 0; n < FN; ++n) acc[m][n] = {0.f, 0.f, 0.f, 0.f};

    for (int k0 = 0; k0 < K; k0 += 32) {
        __syncthreads();
#pragma unroll
        for (int i = 0; i < CA; ++i) {
            int ch = tid + i * 256;
            int row = ch % BM, ks = ch / BM;
            gload16(A + (size_t)(bm + row) * K + k0 + ks * 8, &A_lds[ch * 8]);
        }
#pragma unroll
        for (int i = 0; i < CB; ++i) {
            int ch = tid + i * 256;
            int row = ch % BN, ks = ch / BN;
            gload16(Bm + (size_t)(bn + row) * K + k0 + ks * 8, &B_lds[ch * 8]);
        }
        __syncthreads();

        short8 af[FM], bf[FN];
#pragma unroll
        for (int m = 0; m < FM; ++m)
            af[m] = *reinterpret_cast<const short8*>(&A_lds[(g * BM + wr * WM + m * 16 + ln16) * 8]);
#pragma unroll
        for (int n = 0; n < FN; ++n)
            bf[n] = *reinterpret_cast<const short8*>(&B_lds[(g * BN + wc * WN + n * 16 + ln16) * 8]);
#pragma unroll
        for (int m = 0; m < FM; ++m)
#pragma unroll
            for (int n = 0; n < FN; ++n)
                acc[m][n] = mfma16(af[m], bf[n], acc[m][n]);
    }

#pragma unroll
    for (int m = 0; m < FM; ++m)
#pragma unroll
        for (int n = 0; n < FN; ++n)
#pragma unroll
            for (int r = 0; r < 4; ++r)
                store1<TC>(&C[(size_t)(bm + wr*WM + m*16 + g*4 + r) * N + bn + wc*WN + n*16 + ln16],
                           acc[m][n][r]);
}

// ---------------------------------------------------------------------------
// LayerNorm over L=512 per row, f32.
// ---------------------------------------------------------------------------
__global__ __launch_bounds__(256) void ln_kernel(const float* __restrict__ pre,
                                                 const float* __restrict__ w,
                                                 const float* __restrict__ bias,
                                                 float* __restrict__ out) {
    const int row = blockIdx.x;
    const int tid = threadIdx.x;
    __shared__ float red[256];
    const size_t base = (size_t)row * L_;
    float x0 = pre[base + tid];
    float x1 = pre[base + tid + 256];
    red[tid] = x0 + x1;
    __syncthreads();
    for (int o = 128; o; o >>= 1) { if (tid < o) red[tid] += red[tid + o]; __syncthreads(); }
    float mu = red[0] * (1.0f / L_);
    __syncthreads();
    float d0 = x0 - mu, d1 = x1 - mu;
    red[tid] = d0 * d0 + d1 * d1;
    __syncthreads();
    for (int o = 128; o; o >>= 1) { if (tid < o) red[tid] += red[tid + o]; __syncthreads(); }
    float rstd = rsqrtf(red[0] * (1.0f / L_) + 1e-5f);
    out[base + tid]       = d0 * rstd * w[tid]       + bias[tid];
    out[base + tid + 256] = d1 * rstd * w[tid + 256] + bias[tid + 256];
}

// ---------------------------------------------------------------------------
// f32 -> bf16 convert (4 elems/thread)
// ---------------------------------------------------------------------------
__global__ __launch_bounds__(256) void cvt_bf16(const float* __restrict__ in,
                                                u16* __restrict__ out) {
    size_t i = ((size_t)blockIdx.x * 256 + threadIdx.x) * 4;
    f32x4 v = *reinterpret_cast<const f32x4*>(&in[i]);
    u16x4 o; o[0]=f2bf(v[0]); o[1]=f2bf(v[1]); o[2]=f2bf(v[2]); o[3]=f2bf(v[3]);
    *reinterpret_cast<u16x4*>(&out[i]) = o;
}

// ---------------------------------------------------------------------------
// absorb
// ---------------------------------------------------------------------------
__global__ __launch_bounds__(256) void absorb(const u16* __restrict__ qb,
                                              const float* __restrict__ Wuk,
                                              u16* __restrict__ qp,
                                              int h0col) {
    const int st = blockIdx.x, lt = blockIdx.y, hh = blockIdx.z;
    const int tid = threadIdx.x;
    const int w = tid >> 6, l = tid & 63;
    const int g = l >> 4, ln16 = l & 15;

    __shared__ char A_lds[16384];
    __shared__ char B_lds[16384];

#pragma unroll
    for (int i = 0; i < 4; ++i) {
        int idx = tid + i * 256;
        int row = idx >> 4, c8 = idx & 15;
        int byte = (row * 256 + c8 * 16) ^ ((row & 7) << 4);
        *reinterpret_cast<u16x8*>(A_lds + byte) =
            *reinterpret_cast<const u16x8*>(qb + (size_t)(st*64 + row) * D_ + h0col + hh*128 + c8*8);
    }
#pragma unroll
    for (int i = 0; i < 32; ++i) {
        int idx = tid + i * 256;
        int k = idx >> 6, n = idx & 63;
        int byte = (n * 256 + k * 2) ^ ((n & 7) << 4);
        *reinterpret_cast<u16*>(B_lds + byte) =
            f2bf(Wuk[(size_t)(hh*128 + k) * L_ + lt*64 + n]);
    }
    __syncthreads();

    f32x4 acc[4];
#pragma unroll
    for (int a = 0; a < 4; ++a) acc[a] = {0,0,0,0};

#pragma unroll
    for (int kc = 0; kc < 4; ++kc) {
        const int arow = w*16 + ln16;
        short8 af = *reinterpret_cast<const short8*>(
            A_lds + ((arow*256 + kc*64 + g*16) ^ ((arow & 7) << 4)));
#pragma unroll
        for (int a = 0; a < 4; ++a) {
            const int brow = a*16 + ln16;
            short8 bf = *reinterpret_cast<const short8*>(
                B_lds + ((brow*256 + kc*64 + g*16) ^ ((brow & 7) << 4)));
            acc[a] = mfma16(af, bf, acc[a]);
        }
    }
#pragma unroll
    for (int a = 0; a < 4; ++a)
#pragma unroll
        for (int r = 0; r < 4; ++r)
            qp[((size_t)hh * S_ + st*64 + w*16 + g*4 + r) * L_ + lt*64 + a*16 + ln16] =
                f2bf(acc[a][r]);
}

// ---------------------------------------------------------------------------
// flash_split: r15 balanced-split structure + r18 tweaks:
//  - K h0 DMA issued BEFORE V reg-stage (DMA flight overlaps V load latency)
//  - s_setprio(1) around the three MFMA clusters (T5; m191 precedent)
// ---------------------------------------------------------------------------
__global__ __launch_bounds__(512) void flash_split(const u16* __restrict__ qp,
                                                   const u16* __restrict__ kbf,
                                                   const u16* __restrict__ vbf,
                                                   u16* __restrict__ opart,
                                                   float* __restrict__ ml,
                                                   int h0) {
    const int c  = blockIdx.z;
    const int qt2 = (c < 2) ? (15 - (int)blockIdx.x) : (int)blockIdx.x;
    const int hh = blockIdx.y;
    const int h  = h0 + hh;
    const int tid = threadIdx.x;
    const int w = tid >> 6, l = tid & 63;
    const int g = l >> 4, ln16 = l & 15;

    const int nt = 2*qt2 + 2;
    const int kt0   = (c * nt) >> 2;
    const int ktend = ((c + 1) * nt) >> 2;
    if (ktend <= kt0) {
        if (tid < 128) ml[(size_t)(c*8 + hh)*S_ + qt2*128 + tid] = -3e38f;
        return;
    }

    __shared__ u16 K_lds[16384];
    __shared__ char V_lds[16384];
    __shared__ char P_lds[16384];
    char* P_my = P_lds + w * 2048;

    short8 qreg[16];
    {
        const u16* qbase = qp + ((size_t)hh * S_ + qt2*128 + w*16 + ln16) * L_ + g*8;
#pragma unroll
        for (int kc = 0; kc < 16; ++kc)
            qreg[kc] = *reinterpret_cast<const short8*>(qbase + kc*32);
    }

    float m_run = -3e38f, l_run = 0.f;
    f32x4 acc[8];
#pragma unroll
    for (int cb = 0; cb < 8; ++cb) acc[cb] = {0,0,0,0};

    const int sq = qt2*128 + w*16 + ln16;
    const float scale = 0.08838834764831845f;

    for (int kt = kt0; kt < ktend; ++kt) {
        __syncthreads();
        const u16* ksrc = kbf + (size_t)kt * 64 * L_;
        // ---- issue K half-0 DMA first (in flight during V reg-stage)
#pragma unroll
        for (int i = 0; i < 4; ++i) {
            int ch = tid + i * 512;
            int s = ch >> 6, row = ch & 63;
            gload16(ksrc + (size_t)row * L_ + s*8, &K_lds[ch * 8]);
        }
        // ---- stage V transposed (reg round-trip; overlaps K DMA)
        {
            const u16* vsrc = vbf + (size_t)kt * 64 * D_ + h * DH_;
            const int kv = tid & 63;
#pragma unroll
            for (int p = 0; p < 2; ++p) {
                int dg = (tid >> 6) + p * 8;
                u16x8 v8 = *reinterpret_cast<const u16x8*>(vsrc + (size_t)kv * D_ + dg*8);
#pragma unroll
                for (int j = 0; j < 8; ++j) {
                    int dv = dg*8 + j;
                    *reinterpret_cast<u16*>(V_lds + ((dv*128 + kv*2) ^ (j << 4))) = v8[j];
                }
            }
        }
        __syncthreads();

        f32x4 sacc[4];
#pragma unroll
        for (int a = 0; a < 4; ++a) sacc[a] = {0,0,0,0};
        __builtin_amdgcn_s_setprio(1);
#pragma unroll
        for (int a = 0; a < 4; ++a) {
            const int row = a*16 + ln16;
#pragma unroll
            for (int kc = 0; kc < 8; ++kc) {
                short8 kf = *reinterpret_cast<const short8*>(&K_lds[((kc*4 + g)*64 + row) * 8]);
                sacc[a] = mfma16(kf, qreg[kc], sacc[a]);
            }
        }
        __builtin_amdgcn_s_setprio(0);
        __syncthreads();
        // ---- stage K half 1 (cols 256..511)
#pragma unroll
        for (int i = 0; i < 4; ++i) {
            int ch = tid + i * 512;
            int s = ch >> 6, row = ch & 63;
            gload16(ksrc + (size_t)row * L_ + 256 + s*8, &K_lds[ch * 8]);
        }
        __syncthreads();
        __builtin_amdgcn_s_setprio(1);
#pragma unroll
        for (int a = 0; a < 4; ++a) {
            const int row = a*16 + ln16;
#pragma unroll
            for (int kc = 0; kc < 8; ++kc) {
                short8 kf = *reinterpret_cast<const short8*>(&K_lds[((kc*4 + g)*64 + row) * 8]);
                sacc[a] = mfma16(kf, qreg[8 + kc], sacc[a]);
            }
        }
        __builtin_amdgcn_s_setprio(0);

        float p[4][4];
        float tmax = -3e38f;
#pragma unroll
        for (int a = 0; a < 4; ++a)
#pragma unroll
            for (int r = 0; r < 4; ++r) {
                int t = kt*64 + a*16 + g*4 + r;
                float v = (t <= sq) ? sacc[a][r] * scale : -3e38f;
                p[a][r] = v;
                tmax = fmaxf(tmax, v);
            }
        tmax = fmaxf(tmax, __shfl_xor(tmax, 16, 64));
        tmax = fmaxf(tmax, __shfl_xor(tmax, 32, 64));
        float m_new = fmaxf(m_run, tmax);
        float fac = __expf(m_run - m_new);
        float rsum = 0.f;
#pragma unroll
        for (int a = 0; a < 4; ++a)
#pragma unroll
            for (int r = 0; r < 4; ++r) {
                float e = __expf(p[a][r] - m_new);
                p[a][r] = e;
                rsum += e;
            }
        rsum += __shfl_xor(rsum, 16, 64);
        rsum += __shfl_xor(rsum, 32, 64);
        l_run = l_run * fac + rsum;
        m_run = m_new;

        {
            const int ps = (ln16 & 7) << 4;
#pragma unroll
            for (int a = 0; a < 4; ++a) {
                u16x4 quad;
#pragma unroll
                for (int r = 0; r < 4; ++r) quad[r] = f2bf(p[a][r]);
                *reinterpret_cast<u16x4*>(P_my + ((ln16*128 + a*32 + g*8) ^ ps)) = quad;
            }
        }
        float fr[4];
#pragma unroll
        for (int r = 0; r < 4; ++r) fr[r] = __shfl(fac, g*4 + r, 64);
#pragma unroll
        for (int cb = 0; cb < 8; ++cb)
#pragma unroll
            for (int r = 0; r < 4; ++r) acc[cb][r] *= fr[r];

        __builtin_amdgcn_s_setprio(1);
#pragma unroll
        for (int kc2 = 0; kc2 < 2; ++kc2) {
            short8 pf = *reinterpret_cast<const short8*>(
                P_my + ((ln16*128 + kc2*64 + g*16) ^ ((ln16 & 7) << 4)));
#pragma unroll
            for (int cb = 0; cb < 8; ++cb) {
                const int dv = cb*16 + ln16;
                short8 vf = *reinterpret_cast<const short8*>(
                    V_lds + ((dv*128 + kc2*64 + g*16) ^ ((dv & 7) << 4)));
                acc[cb] = mfma16(pf, vf, acc[cb]);
            }
        }
        __builtin_amdgcn_s_setprio(0);
    }

    float inv = 1.0f / l_run;
    float lse = m_run + __logf(l_run);
    float ir[4];
#pragma unroll
    for (int r = 0; r < 4; ++r) ir[r] = __shfl(inv, g*4 + r, 64);
#pragma unroll
    for (int cb = 0; cb < 8; ++cb)
#pragma unroll
        for (int r = 0; r < 4; ++r) {
            int q = qt2*128 + w*16 + g*4 + r;
            opart[((size_t)(c*8 + hh)*S_ + q)*128 + cb*16 + ln16] = f2bf(acc[cb][r] * ir[r]);
        }
    if (g == 0) ml[(size_t)(c*8 + hh)*S_ + qt2*128 + w*16 + ln16] = lse;
}

// ---------------------------------------------------------------------------
// combine
// ---------------------------------------------------------------------------
__global__ __launch_bounds__(256) void combine(const u16* __restrict__ opart,
                                               const float* __restrict__ ml,
                                               u16* __restrict__ ctx,
                                               int h0) {
    int t = blockIdx.x * 256 + threadIdx.x;
    int qh = t >> 4;
    int q = qh >> 3, hh = qh & 7;
    int dv0 = (t & 15) * 8;

    float ls[4], m = -3e38f;
#pragma unroll
    for (int c = 0; c < 4; ++c) {
        ls[c] = ml[(size_t)(c*8 + hh) * S_ + q];
        m = fmaxf(m, ls[c]);
    }
    float e[4], s = 0.f;
#pragma unroll
    for (int c = 0; c < 4; ++c) { e[c] = __expf(ls[c] - m); s += e[c]; }
    float is = 1.0f / s;

    float accv[8] = {};
#pragma unroll
    for (int c = 0; c < 4; ++c) {
        if (e[c] > 0.f) {
            u16x8 a = *reinterpret_cast<const u16x8*>(
                &opart[((size_t)(c*8 + hh)*S_ + q)*128 + dv0]);
#pragma unroll
            for (int j = 0; j < 8; ++j) accv[j] += e[c] * bf2f(a[j]);
        }
    }
    u16x8 o;
#pragma unroll
    for (int j = 0; j < 8; ++j) o[j] = f2bf(accv[j] * is);
    *reinterpret_cast<u16x8*>(&ctx[(size_t)q * D_ + (h0 + hh) * DH_ + dv0]) = o;
}

// ---------------------------------------------------------------------------
// r18 orchestration == r17 (proven memory plan); q-gemm now 128x64 tiles
// (grid 32x32 = 1024 blocks = 4/CU).
// ---------------------------------------------------------------------------
extern "C" void kernel_launch(void* const* d_in, const int* in_sizes, int n_in,
                              void* d_out, int out_size, void* d_ws, size_t ws_size,
                              hipStream_t stream) {
    const float* x    = (const float*)d_in[0];
    const float* Wq   = (const float*)d_in[1];
    const float* Wdkv = (const float*)d_in[2];
    const float* Wuk  = (const float*)d_in[3];
    const float* Wuv  = (const float*)d_in[4];
    const float* Wo   = (const float*)d_in[5];
    const float* lnw  = (const float*)d_in[6];
    const float* lnb  = (const float*)d_in[7];

    float* out = (float*)d_out;
    float* ckv = out + (size_t)M_ * D_;               // (M,L) real output

    char* ws = (char*)d_ws;
    u16*   xb_bf   = (u16*)(ws);                      // S0 (16 MB)
    u16*   qprime  = (u16*)(ws);                      //   reuse after xb dead
    u16*   wo_bf   = (u16*)(ws);                      //   reuse after qprime dead
    u16*   qb_bf   = (u16*)(ws + (size_t)16777216);   // S1 full-M
    u16*   ctx_b1  = (u16*)(ws + (size_t)16777216);   //   qb_b0 half, after b0 done
    u16*   vb_bf   = (u16*)(ws + (size_t)33554432);   // S2 per batch
    u16*   ckv_bf  = (u16*)(ws + (size_t)41943040);   // S3 full-M (4 MB)
    u16*   wuv_bf  = (u16*)(ws + (size_t)46137344);   // S4 (2 MB)
    float* ml      = (float*)(ws + (size_t)48234496); // S5 (256 KB)

    char*  ob0     = (char*)d_out;                    // out_b0 region (16 MB)
    u16*   wslot   = (u16*)ob0;                       // phase-A weight slot
    float* ckvp    = (float*)(ob0 + 8388608);         // phase-A f32 scratch
    u16*   ctx_b0  = (u16*)(out + (size_t)S_ * D_);   // out_b1 head (8 MB)

    dim3 blk(256);

    // ---- Phase A (batch-fused projections) ----
    cvt_bf16<<<dim3(8192), blk, 0, stream>>>(x, xb_bf);
    cvt_bf16<<<dim3(1024), blk, 0, stream>>>(Wdkv, wslot);
    mgemm<float,64,64,2,2><<<dim3(L_/64, M_/64), blk, 0, stream>>>(xb_bf, wslot, ckvp, L_, D_);
    ln_kernel<<<dim3(M_), blk, 0, stream>>>(ckvp, lnw, lnb, ckv);
    cvt_bf16<<<dim3(2048), blk, 0, stream>>>(ckv, ckv_bf);
    cvt_bf16<<<dim3(4096), blk, 0, stream>>>(Wq, wslot);
    mgemm<u16,128,64,4,1><<<dim3(D_/64, M_/128), blk, 0, stream>>>(xb_bf, wslot, qb_bf, D_, D_);
    cvt_bf16<<<dim3(1024), blk, 0, stream>>>(Wuv, wuv_bf);

    // ---- Per-batch attention + output projection ----
    for (int b = 0; b < B_; ++b) {
        const u16* qb_b    = qb_bf  + (size_t)b * S_ * D_;
        const u16* ckvbf_b = ckv_bf + (size_t)b * S_ * L_;
        float*     outb    = out    + (size_t)b * S_ * D_;
        u16*       opart   = (u16*)outb;                       // 16 MB
        u16*       ctx_b   = (b == 0) ? ctx_b0 : ctx_b1;

        // v_b = ckv_b @ Wuv^T   (128x64 tiles -> 512 blocks)
        mgemm<u16,128,64,4,1><<<dim3(D_/64, S_/128), blk, 0, stream>>>(ckvbf_b, wuv_bf, vb_bf, D_, L_);

        for (int hc = 0; hc < 2; ++hc) {
            absorb<<<dim3(S_/64, L_/64, 8), blk, 0, stream>>>(
                qb_b, Wuk + (size_t)hc * 8 * DH_ * L_, qprime, hc * 8 * DH_);
            flash_split<<<dim3(16, 8, 4), dim3(512), 0, stream>>>(
                qprime, ckvbf_b, vb_bf, opart, ml, hc * 8);
            combine<<<dim3(1024), blk, 0, stream>>>(opart, ml, ctx_b, hc * 8);
        }

        // Wo -> bf16 into dead qprime slot, then out_b = ctx_b @ Wo^T (128x64)
        cvt_bf16<<<dim3(4096), blk, 0, stream>>>(Wo, wo_bf);
        mgemm<float,128,64,4,1><<<dim3(D_/64, S_/128), blk, 0, stream>>>(ctx_b, wo_bf, outb, D_, D_);
    }
}

// Round 20
// 513.278 us; speedup vs baseline: 1.3570x; 1.3570x over previous
//
#include <hip/hip_runtime.h>

#define B_  2
#define S_  2048
#define D_  2048
#define H_  16
#define DH_ 128
#define L_  512
#define M_  (B_*S_)

typedef unsigned short u16;
typedef float f32x4 __attribute__((ext_vector_type(4)));
typedef short short8 __attribute__((ext_vector_type(8)));
typedef u16 u16x4 __attribute__((ext_vector_type(4)));
typedef u16 u16x8 __attribute__((ext_vector_type(8)));

__device__ inline float bf2f(u16 u) {
    union { unsigned int i; float f; } x; x.i = ((unsigned int)u) << 16; return x.f;
}
__device__ inline u16 f2bf(float f) {
    union { float f; unsigned int i; } x; x.f = f;
    unsigned int r = x.i + 0x7FFFu + ((x.i >> 16) & 1u);
    return (u16)(r >> 16);
}
__device__ inline f32x4 mfma16(short8 a, short8 b, f32x4 c) {
    return __builtin_amdgcn_mfma_f32_16x16x32_bf16(a, b, c, 0, 0, 0);
}

typedef const __attribute__((address_space(1))) unsigned int gu32;
typedef __attribute__((address_space(3))) unsigned int lu32;
__device__ inline void gload16(const u16* g, u16* l) {
    __builtin_amdgcn_global_load_lds((gu32*)g, (lu32*)l, 16, 0, 0);
}

template <typename T> __device__ inline void store1(T* p, float v);
template <> __device__ inline void store1<float>(float* p, float v) { *p = v; }
template <> __device__ inline void store1<u16>(u16* p, float v) { *p = f2bf(v); }

// ---------------------------------------------------------------------------
// MFMA GEMM: C[M][N] = A[M][K] @ B[N][K]^T, A/B bf16, f32 accum, TC out.
// Templated tile BM x BN, 4 waves WAVES_M x WAVES_N, BK=32, global_load_lds,
// k-slice LDS layout (conflict-free).  grid = (N/BN, M/BM).
// ---------------------------------------------------------------------------
template <typename TC, int BM, int BN, int WAVES_M, int WAVES_N>
__global__ __launch_bounds__(256) void mgemm(const u16* __restrict__ A,
                                             const u16* __restrict__ Bm,
                                             TC* __restrict__ C,
                                             int N, int K) {
    constexpr int WM = BM / WAVES_M;
    constexpr int WN = BN / WAVES_N;
    constexpr int FM = WM / 16;
    constexpr int FN = WN / 16;
    constexpr int CA = (BM * 4) / 256;
    constexpr int CB = (BN * 4) / 256;

    const int tid = threadIdx.x;
    const int bn = blockIdx.x * BN, bm = blockIdx.y * BM;
    const int w = tid >> 6, l = tid & 63;
    const int wr = w / WAVES_N, wc = w % WAVES_N;
    const int g = l >> 4, ln16 = l & 15;

    __shared__ u16 A_lds[BM * 32];
    __shared__ u16 B_lds[BN * 32];

    f32x4 acc[FM][FN];
#pragma unroll
    for (int m = 0; m < FM; ++m)
#pragma unroll
        for (int n = 0; n < FN; ++n) acc[m][n] = {0.f, 0.f, 0.f, 0.f};

    for (int k0 = 0; k0 < K; k0 += 32) {
        __syncthreads();
#pragma unroll
        for (int i = 0; i < CA; ++i) {
            int ch = tid + i * 256;
            int row = ch % BM, ks = ch / BM;
            gload16(A + (size_t)(bm + row) * K + k0 + ks * 8, &A_lds[ch * 8]);
        }
#pragma unroll
        for (int i = 0; i < CB; ++i) {
            int ch = tid + i * 256;
            int row = ch % BN, ks = ch / BN;
            gload16(Bm + (size_t)(bn + row) * K + k0 + ks * 8, &B_lds[ch * 8]);
        }
        __syncthreads();

        short8 af[FM], bf[FN];
#pragma unroll
        for (int m = 0; m < FM; ++m)
            af[m] = *reinterpret_cast<const short8*>(&A_lds[(g * BM + wr * WM + m * 16 + ln16) * 8]);
#pragma unroll
        for (int n = 0; n < FN; ++n)
            bf[n] = *reinterpret_cast<const short8*>(&B_lds[(g * BN + wc * WN + n * 16 + ln16) * 8]);
#pragma unroll
        for (int m = 0; m < FM; ++m)
#pragma unroll
            for (int n = 0; n < FN; ++n)
                acc[m][n] = mfma16(af[m], bf[n], acc[m][n]);
    }

#pragma unroll
    for (int m = 0; m < FM; ++m)
#pragma unroll
        for (int n = 0; n < FN; ++n)
#pragma unroll
            for (int r = 0; r < 4; ++r)
                store1<TC>(&C[(size_t)(bm + wr*WM + m*16 + g*4 + r) * N + bn + wc*WN + n*16 + ln16],
                           acc[m][n][r]);
}

// ---------------------------------------------------------------------------
// LayerNorm over L=512 per row, f32.
// ---------------------------------------------------------------------------
__global__ __launch_bounds__(256) void ln_kernel(const float* __restrict__ pre,
                                                 const float* __restrict__ w,
                                                 const float* __restrict__ bias,
                                                 float* __restrict__ out) {
    const int row = blockIdx.x;
    const int tid = threadIdx.x;
    __shared__ float red[256];
    const size_t base = (size_t)row * L_;
    float x0 = pre[base + tid];
    float x1 = pre[base + tid + 256];
    red[tid] = x0 + x1;
    __syncthreads();
    for (int o = 128; o; o >>= 1) { if (tid < o) red[tid] += red[tid + o]; __syncthreads(); }
    float mu = red[0] * (1.0f / L_);
    __syncthreads();
    float d0 = x0 - mu, d1 = x1 - mu;
    red[tid] = d0 * d0 + d1 * d1;
    __syncthreads();
    for (int o = 128; o; o >>= 1) { if (tid < o) red[tid] += red[tid + o]; __syncthreads(); }
    float rstd = rsqrtf(red[0] * (1.0f / L_) + 1e-5f);
    out[base + tid]       = d0 * rstd * w[tid]       + bias[tid];
    out[base + tid + 256] = d1 * rstd * w[tid + 256] + bias[tid + 256];
}

// ---------------------------------------------------------------------------
// f32 -> bf16 convert (4 elems/thread)
// ---------------------------------------------------------------------------
__global__ __launch_bounds__(256) void cvt_bf16(const float* __restrict__ in,
                                                u16* __restrict__ out) {
    size_t i = ((size_t)blockIdx.x * 256 + threadIdx.x) * 4;
    f32x4 v = *reinterpret_cast<const f32x4*>(&in[i]);
    u16x4 o; o[0]=f2bf(v[0]); o[1]=f2bf(v[1]); o[2]=f2bf(v[2]); o[3]=f2bf(v[3]);
    *reinterpret_cast<u16x4*>(&out[i]) = o;
}

// ---------------------------------------------------------------------------
// flash_split (r20, UN-ABSORBED): standard d=128 attention per head.
// Q from qb directly (cols h*128..h*128+127); K from kmat (same [t][h*128+d]
// layout as V).  Per kv-tile: K DMA (16 KB) issued first, V reg-staged
// (transposed, swz), ONE barrier pair, 16 QK MFMA + 16 PV MFMA per wave.
// grid (16 bx, 8 hh, 4 c) balanced-split (r15-proven), block 512 (8 waves).
// LDS 48 KB.  Writes normalized partial ctx (bf16) + LSE.
// ---------------------------------------------------------------------------
__global__ __launch_bounds__(512) void flash_split(const u16* __restrict__ qb,
                                                   const u16* __restrict__ kmat,
                                                   const u16* __restrict__ vbf,
                                                   u16* __restrict__ opart,
                                                   float* __restrict__ ml,
                                                   int h0) {
    const int c  = blockIdx.z;
    const int qt2 = (c < 2) ? (15 - (int)blockIdx.x) : (int)blockIdx.x;
    const int hh = blockIdx.y;
    const int h  = h0 + hh;
    const int tid = threadIdx.x;
    const int w = tid >> 6, l = tid & 63;
    const int g = l >> 4, ln16 = l & 15;

    const int nt = 2*qt2 + 2;
    const int kt0   = (c * nt) >> 2;
    const int ktend = ((c + 1) * nt) >> 2;
    if (ktend <= kt0) {
        if (tid < 128) ml[(size_t)(c*8 + hh)*S_ + qt2*128 + tid] = -3e38f;
        return;
    }

    __shared__ u16 K_lds[8192];           // 16 KB: [ks 0..15][row 0..63][8]
    __shared__ char V_lds[16384];         // [dv 0..127][kv 0..63] u16, ^swz
    __shared__ char P_lds[16384];         // 8 waves x 2 KB
    char* P_my = P_lds + w * 2048;

    // Q fragments (d=128): row = qt2*128 + w*16 + ln16
    short8 qreg[4];
    {
        const u16* qbase = qb + (size_t)(qt2*128 + w*16 + ln16) * D_ + h * DH_ + g*8;
#pragma unroll
        for (int kc = 0; kc < 4; ++kc)
            qreg[kc] = *reinterpret_cast<const short8*>(qbase + kc*32);
    }

    float m_run = -3e38f, l_run = 0.f;
    f32x4 acc[8];
#pragma unroll
    for (int cb = 0; cb < 8; ++cb) acc[cb] = {0,0,0,0};

    const int sq = qt2*128 + w*16 + ln16;
    const float scale = 0.08838834764831845f;

    for (int kt = kt0; kt < ktend; ++kt) {
        __syncthreads();
        // ---- K tile DMA (16 KB), issued first so it flies under V staging
        const u16* ksrc = kmat + (size_t)kt * 64 * D_ + h * DH_;
#pragma unroll
        for (int i = 0; i < 2; ++i) {
            int ch = tid + i * 512;
            int row = ch & 63, ks = ch >> 6;
            gload16(ksrc + (size_t)row * D_ + ks * 8, &K_lds[ch * 8]);
        }
        // ---- V tile reg-staged transposed (swz, conflict-free stores)
        {
            const u16* vsrc = vbf + (size_t)kt * 64 * D_ + h * DH_;
            const int kv = tid & 63;
#pragma unroll
            for (int p = 0; p < 2; ++p) {
                int dg = (tid >> 6) + p * 8;
                u16x8 v8 = *reinterpret_cast<const u16x8*>(vsrc + (size_t)kv * D_ + dg*8);
#pragma unroll
                for (int j = 0; j < 8; ++j) {
                    int dv = dg*8 + j;
                    *reinterpret_cast<u16*>(V_lds + ((dv*128 + kv*2) ^ (j << 4))) = v8[j];
                }
            }
        }
        __syncthreads();

        // ---- QK^T (swapped: A=K rows, B=Q rows), d=128 -> 16 MFMA
        f32x4 sacc[4];
#pragma unroll
        for (int a = 0; a < 4; ++a) sacc[a] = {0,0,0,0};
#pragma unroll
        for (int a = 0; a < 4; ++a) {
            const int row = a*16 + ln16;
#pragma unroll
            for (int kc = 0; kc < 4; ++kc) {
                short8 kf = *reinterpret_cast<const short8*>(&K_lds[((kc*4 + g)*64 + row) * 8]);
                sacc[a] = mfma16(kf, qreg[kc], sacc[a]);
            }
        }

        // ---- online softmax (lane owns q = ln16-th row of its wave tile)
        float p[4][4];
        float tmax = -3e38f;
#pragma unroll
        for (int a = 0; a < 4; ++a)
#pragma unroll
            for (int r = 0; r < 4; ++r) {
                int t = kt*64 + a*16 + g*4 + r;
                float v = (t <= sq) ? sacc[a][r] * scale : -3e38f;
                p[a][r] = v;
                tmax = fmaxf(tmax, v);
            }
        tmax = fmaxf(tmax, __shfl_xor(tmax, 16, 64));
        tmax = fmaxf(tmax, __shfl_xor(tmax, 32, 64));
        float m_new = fmaxf(m_run, tmax);
        float fac = __expf(m_run - m_new);
        float rsum = 0.f;
#pragma unroll
        for (int a = 0; a < 4; ++a)
#pragma unroll
            for (int r = 0; r < 4; ++r) {
                float e = __expf(p[a][r] - m_new);
                p[a][r] = e;
                rsum += e;
            }
        rsum += __shfl_xor(rsum, 16, 64);
        rsum += __shfl_xor(rsum, 32, 64);
        l_run = l_run * fac + rsum;
        m_run = m_new;

        // ---- P -> wave-local LDS (bf16)
        {
            const int ps = (ln16 & 7) << 4;
#pragma unroll
            for (int a = 0; a < 4; ++a) {
                u16x4 quad;
#pragma unroll
                for (int r = 0; r < 4; ++r) quad[r] = f2bf(p[a][r]);
                *reinterpret_cast<u16x4*>(P_my + ((ln16*128 + a*32 + g*8) ^ ps)) = quad;
            }
        }
        // ---- rescale ctx
        float fr[4];
#pragma unroll
        for (int r = 0; r < 4; ++r) fr[r] = __shfl(fac, g*4 + r, 64);
#pragma unroll
        for (int cb = 0; cb < 8; ++cb)
#pragma unroll
            for (int r = 0; r < 4; ++r) acc[cb][r] *= fr[r];

        // ---- PV
#pragma unroll
        for (int kc2 = 0; kc2 < 2; ++kc2) {
            short8 pf = *reinterpret_cast<const short8*>(
                P_my + ((ln16*128 + kc2*64 + g*16) ^ ((ln16 & 7) << 4)));
#pragma unroll
            for (int cb = 0; cb < 8; ++cb) {
                const int dv = cb*16 + ln16;
                short8 vf = *reinterpret_cast<const short8*>(
                    V_lds + ((dv*128 + kc2*64 + g*16) ^ ((dv & 7) << 4)));
                acc[cb] = mfma16(pf, vf, acc[cb]);
            }
        }
    }

    // ---- epilogue: normalized partial + LSE
    float inv = 1.0f / l_run;
    float lse = m_run + __logf(l_run);
    float ir[4];
#pragma unroll
    for (int r = 0; r < 4; ++r) ir[r] = __shfl(inv, g*4 + r, 64);
#pragma unroll
    for (int cb = 0; cb < 8; ++cb)
#pragma unroll
        for (int r = 0; r < 4; ++r) {
            int q = qt2*128 + w*16 + g*4 + r;
            opart[((size_t)(c*8 + hh)*S_ + q)*128 + cb*16 + ln16] = f2bf(acc[cb][r] * ir[r]);
        }
    if (g == 0) ml[(size_t)(c*8 + hh)*S_ + qt2*128 + w*16 + ln16] = lse;
}

// ---------------------------------------------------------------------------
// combine: ctx = LSE-weighted blend of the 4 kv-chunk partials.
// ---------------------------------------------------------------------------
__global__ __launch_bounds__(256) void combine(const u16* __restrict__ opart,
                                               const float* __restrict__ ml,
                                               u16* __restrict__ ctx,
                                               int h0) {
    int t = blockIdx.x * 256 + threadIdx.x;
    int qh = t >> 4;
    int q = qh >> 3, hh = qh & 7;
    int dv0 = (t & 15) * 8;

    float ls[4], m = -3e38f;
#pragma unroll
    for (int c = 0; c < 4; ++c) {
        ls[c] = ml[(size_t)(c*8 + hh) * S_ + q];
        m = fmaxf(m, ls[c]);
    }
    float e[4], s = 0.f;
#pragma unroll
    for (int c = 0; c < 4; ++c) { e[c] = __expf(ls[c] - m); s += e[c]; }
    float is = 1.0f / s;

    float accv[8] = {};
#pragma unroll
    for (int c = 0; c < 4; ++c) {
        if (e[c] > 0.f) {
            u16x8 a = *reinterpret_cast<const u16x8*>(
                &opart[((size_t)(c*8 + hh)*S_ + q)*128 + dv0]);
#pragma unroll
            for (int j = 0; j < 8; ++j) accv[j] += e[c] * bf2f(a[j]);
        }
    }
    u16x8 o;
#pragma unroll
    for (int j = 0; j < 8; ++j) o[j] = f2bf(accv[j] * is);
    *reinterpret_cast<u16x8*>(&ctx[(size_t)q * D_ + (h0 + hh) * DH_ + dv0]) = o;
}

// ---------------------------------------------------------------------------
// r20 orchestration (un-absorbed keys).  Memory plan (audited):
// ws: S0 [0,16Mi): xb_bf (phase A) -> kmat full-M (after q-gemm, xb dead)
//     S1 [16Mi,32Mi): qb_bf full-M; ctx_b1 at [16Mi,24Mi) (qb_b0 dead by then)
//     S2 [32Mi,40Mi): vb_bf per batch -> wo_bf after that batch's flash
//     S3 [40Mi,44Mi): ckv_bf full-M   S4 [44Mi,46Mi): wuv_bf
//     S5 [46Mi,46.25Mi): ml
// d_out: out_b0: wslot(Wdkv/Wq/Wuk bf16)[0,8Mi)+ckvp f32[8Mi,16Mi) (phase A)
//        -> opart(b0) -> final out_b0.   out_b1: ctx_b0 [0,8Mi) (during b0)
//        -> opart(b1) -> final out_b1.   ckv tail = real output.
// Liveness: wuk_bf (wslot) consumed by k-gemm before b0 flash writes opart;
// kmat (S0) live through b1 flash; ctx_b0 consumed before opart(b1).
// ---------------------------------------------------------------------------
extern "C" void kernel_launch(void* const* d_in, const int* in_sizes, int n_in,
                              void* d_out, int out_size, void* d_ws, size_t ws_size,
                              hipStream_t stream) {
    const float* x    = (const float*)d_in[0];
    const float* Wq   = (const float*)d_in[1];
    const float* Wdkv = (const float*)d_in[2];
    const float* Wuk  = (const float*)d_in[3];
    const float* Wuv  = (const float*)d_in[4];
    const float* Wo   = (const float*)d_in[5];
    const float* lnw  = (const float*)d_in[6];
    const float* lnb  = (const float*)d_in[7];

    float* out = (float*)d_out;
    float* ckv = out + (size_t)M_ * D_;               // (M,L) real output

    char* ws = (char*)d_ws;
    u16*   xb_bf   = (u16*)(ws);                      // S0 (16 MiB)
    u16*   kmat    = (u16*)(ws);                      //   reuse after xb dead
    u16*   qb_bf   = (u16*)(ws + (size_t)16777216);   // S1 full-M
    u16*   ctx_b1  = (u16*)(ws + (size_t)16777216);   //   qb_b0 half, after b0
    u16*   vb_bf   = (u16*)(ws + (size_t)33554432);   // S2 per batch
    u16*   wo_bf   = (u16*)(ws + (size_t)33554432);   //   reuse after flash(b)
    u16*   ckv_bf  = (u16*)(ws + (size_t)41943040);   // S3 full-M (4 MiB)
    u16*   wuv_bf  = (u16*)(ws + (size_t)46137344);   // S4 (2 MiB)
    float* ml      = (float*)(ws + (size_t)48234496); // S5 (256 KiB)

    char*  ob0     = (char*)d_out;                    // out_b0 region (16 MiB)
    u16*   wslot   = (u16*)ob0;                       // phase-A weight slot
    float* ckvp    = (float*)(ob0 + 8388608);         // phase-A f32 scratch
    u16*   ctx_b0  = (u16*)(out + (size_t)S_ * D_);   // out_b1 head (8 MiB)

    dim3 blk(256);

    // ---- Phase A (batch-fused projections) ----
    cvt_bf16<<<dim3(8192), blk, 0, stream>>>(x, xb_bf);
    cvt_bf16<<<dim3(1024), blk, 0, stream>>>(Wdkv, wslot);
    mgemm<float,64,64,2,2><<<dim3(L_/64, M_/64), blk, 0, stream>>>(xb_bf, wslot, ckvp, L_, D_);
    ln_kernel<<<dim3(M_), blk, 0, stream>>>(ckvp, lnw, lnb, ckv);
    cvt_bf16<<<dim3(2048), blk, 0, stream>>>(ckv, ckv_bf);
    cvt_bf16<<<dim3(4096), blk, 0, stream>>>(Wq, wslot);
    mgemm<u16,128,128,2,2><<<dim3(D_/128, M_/128), blk, 0, stream>>>(xb_bf, wslot, qb_bf, D_, D_);
    cvt_bf16<<<dim3(1024), blk, 0, stream>>>(Wuv, wuv_bf);
    // k materialization: kmat = ckv @ Wuk^T  (full M, 1024 blocks)
    cvt_bf16<<<dim3(1024), blk, 0, stream>>>(Wuk, wslot);
    mgemm<u16,128,64,4,1><<<dim3(D_/64, M_/128), blk, 0, stream>>>(ckv_bf, wslot, kmat, D_, L_);

    // ---- Per-batch attention + output projection ----
    for (int b = 0; b < B_; ++b) {
        const u16* qb_b    = qb_bf  + (size_t)b * S_ * D_;
        const u16* kmat_b  = kmat   + (size_t)b * S_ * D_;
        const u16* ckvbf_b = ckv_bf + (size_t)b * S_ * L_;
        float*     outb    = out    + (size_t)b * S_ * D_;
        u16*       opart   = (u16*)outb;                       // 16 MiB
        u16*       ctx_b   = (b == 0) ? ctx_b0 : ctx_b1;

        // v_b = ckv_b @ Wuv^T   (128x64 tiles -> 512 blocks)
        mgemm<u16,128,64,4,1><<<dim3(D_/64, S_/128), blk, 0, stream>>>(ckvbf_b, wuv_bf, vb_bf, D_, L_);

        for (int hc = 0; hc < 2; ++hc) {
            flash_split<<<dim3(16, 8, 4), dim3(512), 0, stream>>>(
                qb_b, kmat_b, vb_bf, opart, ml, hc * 8);
            combine<<<dim3(1024), blk, 0, stream>>>(opart, ml, ctx_b, hc * 8);
        }

        // Wo -> bf16 into dead vb slot, then out_b = ctx_b @ Wo^T (128x64)
        cvt_bf16<<<dim3(4096), blk, 0, stream>>>(Wo, wo_bf);
        mgemm<float,128,64,4,1><<<dim3(D_/64, S_/128), blk, 0, stream>>>(ctx_b, wo_bf, outb, D_, D_);
    }
}

// Round 21
// 475.387 us; speedup vs baseline: 1.4651x; 1.0797x over previous
//
#include <hip/hip_runtime.h>

#define B_  2
#define S_  2048
#define D_  2048
#define H_  16
#define DH_ 128
#define L_  512
#define M_  (B_*S_)

typedef unsigned short u16;
typedef float f32x4 __attribute__((ext_vector_type(4)));
typedef short short8 __attribute__((ext_vector_type(8)));
typedef u16 u16x4 __attribute__((ext_vector_type(4)));
typedef u16 u16x8 __attribute__((ext_vector_type(8)));

__device__ inline float bf2f(u16 u) {
    union { unsigned int i; float f; } x; x.i = ((unsigned int)u) << 16; return x.f;
}
__device__ inline u16 f2bf(float f) {
    union { float f; unsigned int i; } x; x.f = f;
    unsigned int r = x.i + 0x7FFFu + ((x.i >> 16) & 1u);
    return (u16)(r >> 16);
}
__device__ inline f32x4 mfma16(short8 a, short8 b, f32x4 c) {
    return __builtin_amdgcn_mfma_f32_16x16x32_bf16(a, b, c, 0, 0, 0);
}

typedef const __attribute__((address_space(1))) unsigned int gu32;
typedef __attribute__((address_space(3))) unsigned int lu32;
__device__ inline void gload16(const u16* g, u16* l) {
    __builtin_amdgcn_global_load_lds((gu32*)g, (lu32*)l, 16, 0, 0);
}

template <typename T> __device__ inline void store1(T* p, float v);
template <> __device__ inline void store1<float>(float* p, float v) { *p = v; }
template <> __device__ inline void store1<u16>(u16* p, float v) { *p = f2bf(v); }

// ---------------------------------------------------------------------------
// MFMA GEMM: C[M][N] = A[M][K] @ B[N][K]^T, A/B bf16, f32 accum, TC out.
// r21: BK=64 (32 MFMAs per wave per barrier pair, barriers halved vs BK=32).
// LDS = (BM+BN)*128 bytes (128x128 -> 32 KB; still >=2 blocks/CU).
// k-slice layout [ks 0..7][row][8] -> conflict-free b128 reads.
// grid = (N/BN, M/BM).  K % 64 == 0.
// ---------------------------------------------------------------------------
template <typename TC, int BM, int BN, int WAVES_M, int WAVES_N>
__global__ __launch_bounds__(256) void mgemm(const u16* __restrict__ A,
                                             const u16* __restrict__ Bm,
                                             TC* __restrict__ C,
                                             int N, int K) {
    constexpr int WM = BM / WAVES_M;
    constexpr int WN = BN / WAVES_N;
    constexpr int FM = WM / 16;
    constexpr int FN = WN / 16;
    constexpr int CA = (BM * 8) / 256;     // staging chunks (16B) per thread
    constexpr int CB = (BN * 8) / 256;

    const int tid = threadIdx.x;
    const int bn = blockIdx.x * BN, bm = blockIdx.y * BM;
    const int w = tid >> 6, l = tid & 63;
    const int wr = w / WAVES_N, wc = w % WAVES_N;
    const int g = l >> 4, ln16 = l & 15;

    __shared__ u16 A_lds[BM * 64];
    __shared__ u16 B_lds[BN * 64];

    f32x4 acc[FM][FN];
#pragma unroll
    for (int m = 0; m < FM; ++m)
#pragma unroll
        for (int n = 0; n < FN; ++n) acc[m][n] = {0.f, 0.f, 0.f, 0.f};

    for (int k0 = 0; k0 < K; k0 += 64) {
        __syncthreads();
#pragma unroll
        for (int i = 0; i < CA; ++i) {
            int ch = tid + i * 256;
            int row = ch % BM, ks = ch / BM;
            gload16(A + (size_t)(bm + row) * K + k0 + ks * 8, &A_lds[ch * 8]);
        }
#pragma unroll
        for (int i = 0; i < CB; ++i) {
            int ch = tid + i * 256;
            int row = ch % BN, ks = ch / BN;
            gload16(Bm + (size_t)(bn + row) * K + k0 + ks * 8, &B_lds[ch * 8]);
        }
        __syncthreads();

#pragma unroll
        for (int ko = 0; ko < 2; ++ko) {
            short8 af[FM], bf[FN];
#pragma unroll
            for (int m = 0; m < FM; ++m)
                af[m] = *reinterpret_cast<const short8*>(
                    &A_lds[((ko*4 + g) * BM + wr * WM + m * 16 + ln16) * 8]);
#pragma unroll
            for (int n = 0; n < FN; ++n)
                bf[n] = *reinterpret_cast<const short8*>(
                    &B_lds[((ko*4 + g) * BN + wc * WN + n * 16 + ln16) * 8]);
#pragma unroll
            for (int m = 0; m < FM; ++m)
#pragma unroll
                for (int n = 0; n < FN; ++n)
                    acc[m][n] = mfma16(af[m], bf[n], acc[m][n]);
        }
    }

#pragma unroll
    for (int m = 0; m < FM; ++m)
#pragma unroll
        for (int n = 0; n < FN; ++n)
#pragma unroll
            for (int r = 0; r < 4; ++r)
                store1<TC>(&C[(size_t)(bm + wr*WM + m*16 + g*4 + r) * N + bn + wc*WN + n*16 + ln16],
                           acc[m][n][r]);
}

// ---------------------------------------------------------------------------
// LayerNorm over L=512 per row, f32.  (unchanged)
// ---------------------------------------------------------------------------
__global__ __launch_bounds__(256) void ln_kernel(const float* __restrict__ pre,
                                                 const float* __restrict__ w,
                                                 const float* __restrict__ bias,
                                                 float* __restrict__ out) {
    const int row = blockIdx.x;
    const int tid = threadIdx.x;
    __shared__ float red[256];
    const size_t base = (size_t)row * L_;
    float x0 = pre[base + tid];
    float x1 = pre[base + tid + 256];
    red[tid] = x0 + x1;
    __syncthreads();
    for (int o = 128; o; o >>= 1) { if (tid < o) red[tid] += red[tid + o]; __syncthreads(); }
    float mu = red[0] * (1.0f / L_);
    __syncthreads();
    float d0 = x0 - mu, d1 = x1 - mu;
    red[tid] = d0 * d0 + d1 * d1;
    __syncthreads();
    for (int o = 128; o; o >>= 1) { if (tid < o) red[tid] += red[tid + o]; __syncthreads(); }
    float rstd = rsqrtf(red[0] * (1.0f / L_) + 1e-5f);
    out[base + tid]       = d0 * rstd * w[tid]       + bias[tid];
    out[base + tid + 256] = d1 * rstd * w[tid + 256] + bias[tid + 256];
}

// ---------------------------------------------------------------------------
// f32 -> bf16 convert (4 elems/thread)  (unchanged)
// ---------------------------------------------------------------------------
__global__ __launch_bounds__(256) void cvt_bf16(const float* __restrict__ in,
                                                u16* __restrict__ out) {
    size_t i = ((size_t)blockIdx.x * 256 + threadIdx.x) * 4;
    f32x4 v = *reinterpret_cast<const f32x4*>(&in[i]);
    u16x4 o; o[0]=f2bf(v[0]); o[1]=f2bf(v[1]); o[2]=f2bf(v[2]); o[3]=f2bf(v[3]);
    *reinterpret_cast<u16x4*>(&out[i]) = o;
}

// ---------------------------------------------------------------------------
// flash_split (r21, merged heads): grid (16 bx, 16 hh, 2 c), block 512.
// qt2 = (c==0) ? 15-bx : bx -> co-resident pairs (n, n+256) complementary.
// Chunk c covers [c*nt/2, (c+1)*nt/2) of nt=2*qt2+2 tiles (never empty).
// Per kv-tile: K DMA (16 KB) first, V reg-staged transposed (swz), 1 barrier
// pair, 16 QK + 16 PV MFMA per wave.  LDS 48 KB.
// ---------------------------------------------------------------------------
__global__ __launch_bounds__(512) void flash_split(const u16* __restrict__ qb,
                                                   const u16* __restrict__ kmat,
                                                   const u16* __restrict__ vbf,
                                                   u16* __restrict__ opart,
                                                   float* __restrict__ ml) {
    const int c  = blockIdx.z;
    const int qt2 = (c == 0) ? (15 - (int)blockIdx.x) : (int)blockIdx.x;
    const int hh = blockIdx.y;                 // 0..15
    const int tid = threadIdx.x;
    const int w = tid >> 6, l = tid & 63;
    const int g = l >> 4, ln16 = l & 15;

    const int nt = 2*qt2 + 2;
    const int kt0   = (c * nt) >> 1;
    const int ktend = ((c + 1) * nt) >> 1;

    __shared__ u16 K_lds[8192];           // [ks 0..15][row 0..63][8]
    __shared__ char V_lds[16384];         // [dv 0..127][kv 0..63] u16, ^swz
    __shared__ char P_lds[16384];         // 8 waves x 2 KB
    char* P_my = P_lds + w * 2048;

    short8 qreg[4];
    {
        const u16* qbase = qb + (size_t)(qt2*128 + w*16 + ln16) * D_ + hh * DH_ + g*8;
#pragma unroll
        for (int kc = 0; kc < 4; ++kc)
            qreg[kc] = *reinterpret_cast<const short8*>(qbase + kc*32);
    }

    float m_run = -3e38f, l_run = 0.f;
    f32x4 acc[8];
#pragma unroll
    for (int cb = 0; cb < 8; ++cb) acc[cb] = {0,0,0,0};

    const int sq = qt2*128 + w*16 + ln16;
    const float scale = 0.08838834764831845f;

    for (int kt = kt0; kt < ktend; ++kt) {
        __syncthreads();
        const u16* ksrc = kmat + (size_t)kt * 64 * D_ + hh * DH_;
#pragma unroll
        for (int i = 0; i < 2; ++i) {
            int ch = tid + i * 512;
            int row = ch & 63, ks = ch >> 6;
            gload16(ksrc + (size_t)row * D_ + ks * 8, &K_lds[ch * 8]);
        }
        {
            const u16* vsrc = vbf + (size_t)kt * 64 * D_ + hh * DH_;
            const int kv = tid & 63;
#pragma unroll
            for (int p = 0; p < 2; ++p) {
                int dg = (tid >> 6) + p * 8;
                u16x8 v8 = *reinterpret_cast<const u16x8*>(vsrc + (size_t)kv * D_ + dg*8);
#pragma unroll
                for (int j = 0; j < 8; ++j) {
                    int dv = dg*8 + j;
                    *reinterpret_cast<u16*>(V_lds + ((dv*128 + kv*2) ^ (j << 4))) = v8[j];
                }
            }
        }
        __syncthreads();

        f32x4 sacc[4];
#pragma unroll
        for (int a = 0; a < 4; ++a) sacc[a] = {0,0,0,0};
#pragma unroll
        for (int a = 0; a < 4; ++a) {
            const int row = a*16 + ln16;
#pragma unroll
            for (int kc = 0; kc < 4; ++kc) {
                short8 kf = *reinterpret_cast<const short8*>(&K_lds[((kc*4 + g)*64 + row) * 8]);
                sacc[a] = mfma16(kf, qreg[kc], sacc[a]);
            }
        }

        float p[4][4];
        float tmax = -3e38f;
#pragma unroll
        for (int a = 0; a < 4; ++a)
#pragma unroll
            for (int r = 0; r < 4; ++r) {
                int t = kt*64 + a*16 + g*4 + r;
                float v = (t <= sq) ? sacc[a][r] * scale : -3e38f;
                p[a][r] = v;
                tmax = fmaxf(tmax, v);
            }
        tmax = fmaxf(tmax, __shfl_xor(tmax, 16, 64));
        tmax = fmaxf(tmax, __shfl_xor(tmax, 32, 64));
        float m_new = fmaxf(m_run, tmax);
        float fac = __expf(m_run - m_new);
        float rsum = 0.f;
#pragma unroll
        for (int a = 0; a < 4; ++a)
#pragma unroll
            for (int r = 0; r < 4; ++r) {
                float e = __expf(p[a][r] - m_new);
                p[a][r] = e;
                rsum += e;
            }
        rsum += __shfl_xor(rsum, 16, 64);
        rsum += __shfl_xor(rsum, 32, 64);
        l_run = l_run * fac + rsum;
        m_run = m_new;

        {
            const int ps = (ln16 & 7) << 4;
#pragma unroll
            for (int a = 0; a < 4; ++a) {
                u16x4 quad;
#pragma unroll
                for (int r = 0; r < 4; ++r) quad[r] = f2bf(p[a][r]);
                *reinterpret_cast<u16x4*>(P_my + ((ln16*128 + a*32 + g*8) ^ ps)) = quad;
            }
        }
        float fr[4];
#pragma unroll
        for (int r = 0; r < 4; ++r) fr[r] = __shfl(fac, g*4 + r, 64);
#pragma unroll
        for (int cb = 0; cb < 8; ++cb)
#pragma unroll
            for (int r = 0; r < 4; ++r) acc[cb][r] *= fr[r];

#pragma unroll
        for (int kc2 = 0; kc2 < 2; ++kc2) {
            short8 pf = *reinterpret_cast<const short8*>(
                P_my + ((ln16*128 + kc2*64 + g*16) ^ ((ln16 & 7) << 4)));
#pragma unroll
            for (int cb = 0; cb < 8; ++cb) {
                const int dv = cb*16 + ln16;
                short8 vf = *reinterpret_cast<const short8*>(
                    V_lds + ((dv*128 + kc2*64 + g*16) ^ ((dv & 7) << 4)));
                acc[cb] = mfma16(pf, vf, acc[cb]);
            }
        }
    }

    float inv = 1.0f / l_run;
    float lse = m_run + __logf(l_run);
    float ir[4];
#pragma unroll
    for (int r = 0; r < 4; ++r) ir[r] = __shfl(inv, g*4 + r, 64);
#pragma unroll
    for (int cb = 0; cb < 8; ++cb)
#pragma unroll
        for (int r = 0; r < 4; ++r) {
            int q = qt2*128 + w*16 + g*4 + r;
            opart[((size_t)(c*16 + hh)*S_ + q)*128 + cb*16 + ln16] = f2bf(acc[cb][r] * ir[r]);
        }
    if (g == 0) ml[(size_t)(c*16 + hh)*S_ + qt2*128 + w*16 + ln16] = lse;
}

// ---------------------------------------------------------------------------
// combine (r21): blend 2 chunk partials, 16 heads.  grid 2048 x 256 thr.
// ---------------------------------------------------------------------------
__global__ __launch_bounds__(256) void combine(const u16* __restrict__ opart,
                                               const float* __restrict__ ml,
                                               u16* __restrict__ ctx) {
    int t = blockIdx.x * 256 + threadIdx.x;
    int qh = t >> 4;
    int q = qh >> 4, hh = qh & 15;
    int dv0 = (t & 15) * 8;

    float ls0 = ml[(size_t)hh * S_ + q];
    float ls1 = ml[(size_t)(16 + hh) * S_ + q];
    float m = fmaxf(ls0, ls1);
    float e0 = __expf(ls0 - m), e1 = __expf(ls1 - m);
    float is = 1.0f / (e0 + e1);

    u16x8 a = *reinterpret_cast<const u16x8*>(&opart[((size_t)hh*S_ + q)*128 + dv0]);
    u16x8 b = *reinterpret_cast<const u16x8*>(&opart[((size_t)(16 + hh)*S_ + q)*128 + dv0]);
    u16x8 o;
#pragma unroll
    for (int j = 0; j < 8; ++j)
        o[j] = f2bf((e0 * bf2f(a[j]) + e1 * bf2f(b[j])) * is);
    *reinterpret_cast<u16x8*>(&ctx[(size_t)q * D_ + hh * DH_ + dv0]) = o;
}

// ---------------------------------------------------------------------------
// r21 orchestration (memory plan identical to r20; flash/combine merged):
// ws: S0 [0,16Mi): xb_bf (phase A) -> kmat full-M
//     S1 [16Mi,32Mi): qb_bf full-M; ctx_b1 at [16Mi,24Mi) after b0 done
//     S2 [32Mi,40Mi): vb_bf per batch -> wo_bf after that batch's flash
//     S3 [40Mi,44Mi): ckv_bf  S4 [44Mi,46Mi): wuv_bf  S5 [46Mi,46.25Mi): ml
// d_out: out_b0 = wslot+ckvp (phase A) -> opart(b0) -> final.  out_b1 head =
// ctx_b0 -> opart(b1) -> final.  ckv tail = real output.
// ---------------------------------------------------------------------------
extern "C" void kernel_launch(void* const* d_in, const int* in_sizes, int n_in,
                              void* d_out, int out_size, void* d_ws, size_t ws_size,
                              hipStream_t stream) {
    const float* x    = (const float*)d_in[0];
    const float* Wq   = (const float*)d_in[1];
    const float* Wdkv = (const float*)d_in[2];
    const float* Wuk  = (const float*)d_in[3];
    const float* Wuv  = (const float*)d_in[4];
    const float* Wo   = (const float*)d_in[5];
    const float* lnw  = (const float*)d_in[6];
    const float* lnb  = (const float*)d_in[7];

    float* out = (float*)d_out;
    float* ckv = out + (size_t)M_ * D_;               // (M,L) real output

    char* ws = (char*)d_ws;
    u16*   xb_bf   = (u16*)(ws);                      // S0 (16 MiB)
    u16*   kmat    = (u16*)(ws);                      //   reuse after xb dead
    u16*   qb_bf   = (u16*)(ws + (size_t)16777216);   // S1 full-M
    u16*   ctx_b1  = (u16*)(ws + (size_t)16777216);   //   qb_b0 half, after b0
    u16*   vb_bf   = (u16*)(ws + (size_t)33554432);   // S2 per batch
    u16*   wo_bf   = (u16*)(ws + (size_t)33554432);   //   reuse after flash(b)
    u16*   ckv_bf  = (u16*)(ws + (size_t)41943040);   // S3 full-M (4 MiB)
    u16*   wuv_bf  = (u16*)(ws + (size_t)46137344);   // S4 (2 MiB)
    float* ml      = (float*)(ws + (size_t)48234496); // S5 (256 KiB)

    char*  ob0     = (char*)d_out;                    // out_b0 region (16 MiB)
    u16*   wslot   = (u16*)ob0;                       // phase-A weight slot
    float* ckvp    = (float*)(ob0 + 8388608);         // phase-A f32 scratch
    u16*   ctx_b0  = (u16*)(out + (size_t)S_ * D_);   // out_b1 head (8 MiB)

    dim3 blk(256);

    // ---- Phase A (batch-fused projections) ----
    cvt_bf16<<<dim3(8192), blk, 0, stream>>>(x, xb_bf);
    cvt_bf16<<<dim3(1024), blk, 0, stream>>>(Wdkv, wslot);
    mgemm<float,64,64,2,2><<<dim3(L_/64, M_/64), blk, 0, stream>>>(xb_bf, wslot, ckvp, L_, D_);
    ln_kernel<<<dim3(M_), blk, 0, stream>>>(ckvp, lnw, lnb, ckv);
    cvt_bf16<<<dim3(2048), blk, 0, stream>>>(ckv, ckv_bf);
    cvt_bf16<<<dim3(4096), blk, 0, stream>>>(Wq, wslot);
    mgemm<u16,128,128,2,2><<<dim3(D_/128, M_/128), blk, 0, stream>>>(xb_bf, wslot, qb_bf, D_, D_);
    cvt_bf16<<<dim3(1024), blk, 0, stream>>>(Wuv, wuv_bf);
    // k materialization: kmat = ckv @ Wuk^T  (full M)
    cvt_bf16<<<dim3(1024), blk, 0, stream>>>(Wuk, wslot);
    mgemm<u16,128,64,4,1><<<dim3(D_/64, M_/128), blk, 0, stream>>>(ckv_bf, wslot, kmat, D_, L_);

    // ---- Per-batch attention + output projection ----
    for (int b = 0; b < B_; ++b) {
        const u16* qb_b    = qb_bf  + (size_t)b * S_ * D_;
        const u16* kmat_b  = kmat   + (size_t)b * S_ * D_;
        const u16* ckvbf_b = ckv_bf + (size_t)b * S_ * L_;
        float*     outb    = out    + (size_t)b * S_ * D_;
        u16*       opart   = (u16*)outb;                       // 16 MiB
        u16*       ctx_b   = (b == 0) ? ctx_b0 : ctx_b1;

        // v_b = ckv_b @ Wuv^T
        mgemm<u16,128,64,4,1><<<dim3(D_/64, S_/128), blk, 0, stream>>>(ckvbf_b, wuv_bf, vb_bf, D_, L_);

        // fused 16-head flash + combine
        flash_split<<<dim3(16, 16, 2), dim3(512), 0, stream>>>(
            qb_b, kmat_b, vb_bf, opart, ml);
        combine<<<dim3(2048), blk, 0, stream>>>(opart, ml, ctx_b);

        // Wo -> bf16 into dead vb slot, then out_b = ctx_b @ Wo^T
        cvt_bf16<<<dim3(4096), blk, 0, stream>>>(Wo, wo_bf);
        mgemm<float,128,64,4,1><<<dim3(D_/64, S_/128), blk, 0, stream>>>(ctx_b, wo_bf, outb, D_, D_);
    }
}

// Round 22
// 473.669 us; speedup vs baseline: 1.4704x; 1.0036x over previous
//
#include <hip/hip_runtime.h>

#define B_  2
#define S_  2048
#define D_  2048
#define H_  16
#define DH_ 128
#define L_  512
#define M_  (B_*S_)

typedef unsigned short u16;
typedef float f32x4 __attribute__((ext_vector_type(4)));
typedef short short8 __attribute__((ext_vector_type(8)));
typedef u16 u16x4 __attribute__((ext_vector_type(4)));
typedef u16 u16x8 __attribute__((ext_vector_type(8)));

__device__ inline float bf2f(u16 u) {
    union { unsigned int i; float f; } x; x.i = ((unsigned int)u) << 16; return x.f;
}
__device__ inline u16 f2bf(float f) {
    union { float f; unsigned int i; } x; x.f = f;
    unsigned int r = x.i + 0x7FFFu + ((x.i >> 16) & 1u);
    return (u16)(r >> 16);
}
__device__ inline f32x4 mfma16(short8 a, short8 b, f32x4 c) {
    return __builtin_amdgcn_mfma_f32_16x16x32_bf16(a, b, c, 0, 0, 0);
}

typedef const __attribute__((address_space(1))) unsigned int gu32;
typedef __attribute__((address_space(3))) unsigned int lu32;
__device__ inline void gload16(const u16* g, u16* l) {
    __builtin_amdgcn_global_load_lds((gu32*)g, (lu32*)l, 16, 0, 0);
}

template <typename T> __device__ inline void store1(T* p, float v);
template <> __device__ inline void store1<float>(float* p, float v) { *p = v; }
template <> __device__ inline void store1<u16>(u16* p, float v) { *p = f2bf(v); }

// ---------------------------------------------------------------------------
// MFMA GEMM: C[M][N] = A[M][K] @ B[N][K]^T, A/B bf16, f32 accum, TC out.
// BK=64 (r21-proven): 32 MFMAs per wave per barrier pair.
// LDS = (BM+BN)*128 B.  k-slice layout [ks][row][8], conflict-free.
// grid = (N/BN, M/BM).  K % 64 == 0.
// ---------------------------------------------------------------------------
template <typename TC, int BM, int BN, int WAVES_M, int WAVES_N>
__global__ __launch_bounds__(256) void mgemm(const u16* __restrict__ A,
                                             const u16* __restrict__ Bm,
                                             TC* __restrict__ C,
                                             int N, int K) {
    constexpr int WM = BM / WAVES_M;
    constexpr int WN = BN / WAVES_N;
    constexpr int FM = WM / 16;
    constexpr int FN = WN / 16;
    constexpr int CA = (BM * 8) / 256;
    constexpr int CB = (BN * 8) / 256;

    const int tid = threadIdx.x;
    const int bn = blockIdx.x * BN, bm = blockIdx.y * BM;
    const int w = tid >> 6, l = tid & 63;
    const int wr = w / WAVES_N, wc = w % WAVES_N;
    const int g = l >> 4, ln16 = l & 15;

    __shared__ u16 A_lds[BM * 64];
    __shared__ u16 B_lds[BN * 64];

    f32x4 acc[FM][FN];
#pragma unroll
    for (int m = 0; m < FM; ++m)
#pragma unroll
        for (int n = 0; n < FN; ++n) acc[m][n] = {0.f, 0.f, 0.f, 0.f};

    for (int k0 = 0; k0 < K; k0 += 64) {
        __syncthreads();
#pragma unroll
        for (int i = 0; i < CA; ++i) {
            int ch = tid + i * 256;
            int row = ch % BM, ks = ch / BM;
            gload16(A + (size_t)(bm + row) * K + k0 + ks * 8, &A_lds[ch * 8]);
        }
#pragma unroll
        for (int i = 0; i < CB; ++i) {
            int ch = tid + i * 256;
            int row = ch % BN, ks = ch / BN;
            gload16(Bm + (size_t)(bn + row) * K + k0 + ks * 8, &B_lds[ch * 8]);
        }
        __syncthreads();

#pragma unroll
        for (int ko = 0; ko < 2; ++ko) {
            short8 af[FM], bf[FN];
#pragma unroll
            for (int m = 0; m < FM; ++m)
                af[m] = *reinterpret_cast<const short8*>(
                    &A_lds[((ko*4 + g) * BM + wr * WM + m * 16 + ln16) * 8]);
#pragma unroll
            for (int n = 0; n < FN; ++n)
                bf[n] = *reinterpret_cast<const short8*>(
                    &B_lds[((ko*4 + g) * BN + wc * WN + n * 16 + ln16) * 8]);
#pragma unroll
            for (int m = 0; m < FM; ++m)
#pragma unroll
                for (int n = 0; n < FN; ++n)
                    acc[m][n] = mfma16(af[m], bf[n], acc[m][n]);
        }
    }

#pragma unroll
    for (int m = 0; m < FM; ++m)
#pragma unroll
        for (int n = 0; n < FN; ++n)
#pragma unroll
            for (int r = 0; r < 4; ++r)
                store1<TC>(&C[(size_t)(bm + wr*WM + m*16 + g*4 + r) * N + bn + wc*WN + n*16 + ln16],
                           acc[m][n][r]);
}

// ---------------------------------------------------------------------------
// LayerNorm over L=512 per row, f32.  (unchanged)
// ---------------------------------------------------------------------------
__global__ __launch_bounds__(256) void ln_kernel(const float* __restrict__ pre,
                                                 const float* __restrict__ w,
                                                 const float* __restrict__ bias,
                                                 float* __restrict__ out) {
    const int row = blockIdx.x;
    const int tid = threadIdx.x;
    __shared__ float red[256];
    const size_t base = (size_t)row * L_;
    float x0 = pre[base + tid];
    float x1 = pre[base + tid + 256];
    red[tid] = x0 + x1;
    __syncthreads();
    for (int o = 128; o; o >>= 1) { if (tid < o) red[tid] += red[tid + o]; __syncthreads(); }
    float mu = red[0] * (1.0f / L_);
    __syncthreads();
    float d0 = x0 - mu, d1 = x1 - mu;
    red[tid] = d0 * d0 + d1 * d1;
    __syncthreads();
    for (int o = 128; o; o >>= 1) { if (tid < o) red[tid] += red[tid + o]; __syncthreads(); }
    float rstd = rsqrtf(red[0] * (1.0f / L_) + 1e-5f);
    out[base + tid]       = d0 * rstd * w[tid]       + bias[tid];
    out[base + tid + 256] = d1 * rstd * w[tid + 256] + bias[tid + 256];
}

// ---------------------------------------------------------------------------
// f32 -> bf16 convert (4 elems/thread)  (unchanged)
// ---------------------------------------------------------------------------
__global__ __launch_bounds__(256) void cvt_bf16(const float* __restrict__ in,
                                                u16* __restrict__ out) {
    size_t i = ((size_t)blockIdx.x * 256 + threadIdx.x) * 4;
    f32x4 v = *reinterpret_cast<const f32x4*>(&in[i]);
    u16x4 o; o[0]=f2bf(v[0]); o[1]=f2bf(v[1]); o[2]=f2bf(v[2]); o[3]=f2bf(v[3]);
    *reinterpret_cast<u16x4*>(&out[i]) = o;
}

// ---------------------------------------------------------------------------
// flash_split (r22): 2-phase double-buffered pipeline.
// grid (16 bx, 16 hh, 2 c), block 512 (8 waves).  qt2 complementary pairing.
// LDS 80 KB: K[2] 32K + V[2] 32K + P 16K -> 2 blocks/CU (160 KB).
// Per tile ONE barrier; K DMA + V reg-loads for t+1 issued before t's
// compute (staging flies under QK/softmax/PV); V regs written to the
// alternate buffer after PV (issue-early / write-late, T14).
// ---------------------------------------------------------------------------
__global__ __launch_bounds__(512) void flash_split(const u16* __restrict__ qb,
                                                   const u16* __restrict__ kmat,
                                                   const u16* __restrict__ vbf,
                                                   u16* __restrict__ opart,
                                                   float* __restrict__ ml) {
    const int c  = blockIdx.z;
    const int qt2 = (c == 0) ? (15 - (int)blockIdx.x) : (int)blockIdx.x;
    const int hh = blockIdx.y;
    const int tid = threadIdx.x;
    const int w = tid >> 6, l = tid & 63;
    const int g = l >> 4, ln16 = l & 15;

    const int nt = 2*qt2 + 2;
    const int kt0   = (c * nt) >> 1;
    const int ktend = ((c + 1) * nt) >> 1;

    __shared__ u16 K_lds[2][8192];        // [ks 0..15][row 0..63][8]
    __shared__ char V_lds[2][16384];      // [dv 0..127][kv 0..63] u16, ^swz
    __shared__ char P_lds[16384];         // 8 waves x 2 KB (wave-private)
    char* P_my = P_lds + w * 2048;

    short8 qreg[4];
    {
        const u16* qbase = qb + (size_t)(qt2*128 + w*16 + ln16) * D_ + hh * DH_ + g*8;
#pragma unroll
        for (int kc = 0; kc < 4; ++kc)
            qreg[kc] = *reinterpret_cast<const short8*>(qbase + kc*32);
    }

    const int kv = tid & 63;
    const int dg = tid >> 6;              // 0..7

    // ---- prologue: stage tile kt0 into buffer 0
    {
        const u16* ksrc = kmat + (size_t)kt0 * 64 * D_ + hh * DH_;
#pragma unroll
        for (int i = 0; i < 2; ++i) {
            int ch = tid + i * 512;
            int row = ch & 63, ks = ch >> 6;
            gload16(ksrc + (size_t)row * D_ + ks * 8, &K_lds[0][ch * 8]);
        }
        const u16* vsrc = vbf + (size_t)kt0 * 64 * D_ + hh * DH_;
        u16x8 v0 = *reinterpret_cast<const u16x8*>(vsrc + (size_t)kv * D_ + dg*8);
        u16x8 v1 = *reinterpret_cast<const u16x8*>(vsrc + (size_t)kv * D_ + (dg+8)*8);
#pragma unroll
        for (int j = 0; j < 8; ++j) {
            int dva = dg*8 + j, dvb = (dg+8)*8 + j;
            *reinterpret_cast<u16*>(&V_lds[0][0] + ((dva*128 + kv*2) ^ (j << 4))) = v0[j];
            *reinterpret_cast<u16*>(&V_lds[0][0] + ((dvb*128 + kv*2) ^ (j << 4))) = v1[j];
        }
    }

    float m_run = -3e38f, l_run = 0.f;
    f32x4 acc[8];
#pragma unroll
    for (int cb = 0; cb < 8; ++cb) acc[cb] = {0,0,0,0};

    const int sq = qt2*128 + w*16 + ln16;
    const float scale = 0.08838834764831845f;

    int cur = 0;
    for (int kt = kt0; kt < ktend; ++kt) {
        __syncthreads();                  // buf[cur] staging complete

        // ---- prefetch tile kt+1 into buf[cur^1] (issue-early)
        const bool pre = (kt + 1 < ktend);
        u16x8 vp0, vp1;
        if (pre) {
            const u16* ksrc = kmat + (size_t)(kt+1) * 64 * D_ + hh * DH_;
#pragma unroll
            for (int i = 0; i < 2; ++i) {
                int ch = tid + i * 512;
                int row = ch & 63, ks = ch >> 6;
                gload16(ksrc + (size_t)row * D_ + ks * 8, &K_lds[cur^1][ch * 8]);
            }
            const u16* vsrc = vbf + (size_t)(kt+1) * 64 * D_ + hh * DH_;
            vp0 = *reinterpret_cast<const u16x8*>(vsrc + (size_t)kv * D_ + dg*8);
            vp1 = *reinterpret_cast<const u16x8*>(vsrc + (size_t)kv * D_ + (dg+8)*8);
        }

        // ---- QK^T on buf[cur]
        const u16* Kc = &K_lds[cur][0];
        f32x4 sacc[4];
#pragma unroll
        for (int a = 0; a < 4; ++a) sacc[a] = {0,0,0,0};
#pragma unroll
        for (int a = 0; a < 4; ++a) {
            const int row = a*16 + ln16;
#pragma unroll
            for (int kc = 0; kc < 4; ++kc) {
                short8 kf = *reinterpret_cast<const short8*>(&Kc[((kc*4 + g)*64 + row) * 8]);
                sacc[a] = mfma16(kf, qreg[kc], sacc[a]);
            }
        }

        // ---- online softmax
        float p[4][4];
        float tmax = -3e38f;
#pragma unroll
        for (int a = 0; a < 4; ++a)
#pragma unroll
            for (int r = 0; r < 4; ++r) {
                int t = kt*64 + a*16 + g*4 + r;
                float v = (t <= sq) ? sacc[a][r] * scale : -3e38f;
                p[a][r] = v;
                tmax = fmaxf(tmax, v);
            }
        tmax = fmaxf(tmax, __shfl_xor(tmax, 16, 64));
        tmax = fmaxf(tmax, __shfl_xor(tmax, 32, 64));
        float m_new = fmaxf(m_run, tmax);
        float fac = __expf(m_run - m_new);
        float rsum = 0.f;
#pragma unroll
        for (int a = 0; a < 4; ++a)
#pragma unroll
            for (int r = 0; r < 4; ++r) {
                float e = __expf(p[a][r] - m_new);
                p[a][r] = e;
                rsum += e;
            }
        rsum += __shfl_xor(rsum, 16, 64);
        rsum += __shfl_xor(rsum, 32, 64);
        l_run = l_run * fac + rsum;
        m_run = m_new;

        // ---- P -> wave-private LDS (bf16)
        {
            const int ps = (ln16 & 7) << 4;
#pragma unroll
            for (int a = 0; a < 4; ++a) {
                u16x4 quad;
#pragma unroll
                for (int r = 0; r < 4; ++r) quad[r] = f2bf(p[a][r]);
                *reinterpret_cast<u16x4*>(P_my + ((ln16*128 + a*32 + g*8) ^ ps)) = quad;
            }
        }
        // ---- rescale ctx
        float fr[4];
#pragma unroll
        for (int r = 0; r < 4; ++r) fr[r] = __shfl(fac, g*4 + r, 64);
#pragma unroll
        for (int cb = 0; cb < 8; ++cb)
#pragma unroll
            for (int r = 0; r < 4; ++r) acc[cb][r] *= fr[r];

        // ---- PV on buf[cur]
        const char* Vc = &V_lds[cur][0];
#pragma unroll
        for (int kc2 = 0; kc2 < 2; ++kc2) {
            short8 pf = *reinterpret_cast<const short8*>(
                P_my + ((ln16*128 + kc2*64 + g*16) ^ ((ln16 & 7) << 4)));
#pragma unroll
            for (int cb = 0; cb < 8; ++cb) {
                const int dv = cb*16 + ln16;
                short8 vf = *reinterpret_cast<const short8*>(
                    Vc + ((dv*128 + kc2*64 + g*16) ^ ((dv & 7) << 4)));
                acc[cb] = mfma16(pf, vf, acc[cb]);
            }
        }

        // ---- write prefetched V regs into buf[cur^1] (write-late)
        if (pre) {
            char* Vn = &V_lds[cur^1][0];
#pragma unroll
            for (int j = 0; j < 8; ++j) {
                int dva = dg*8 + j, dvb = (dg+8)*8 + j;
                *reinterpret_cast<u16*>(Vn + ((dva*128 + kv*2) ^ (j << 4))) = vp0[j];
                *reinterpret_cast<u16*>(Vn + ((dvb*128 + kv*2) ^ (j << 4))) = vp1[j];
            }
        }
        cur ^= 1;
    }

    // ---- epilogue: normalized partial + LSE
    float inv = 1.0f / l_run;
    float lse = m_run + __logf(l_run);
    float ir[4];
#pragma unroll
    for (int r = 0; r < 4; ++r) ir[r] = __shfl(inv, g*4 + r, 64);
#pragma unroll
    for (int cb = 0; cb < 8; ++cb)
#pragma unroll
        for (int r = 0; r < 4; ++r) {
            int q = qt2*128 + w*16 + g*4 + r;
            opart[((size_t)(c*16 + hh)*S_ + q)*128 + cb*16 + ln16] = f2bf(acc[cb][r] * ir[r]);
        }
    if (g == 0) ml[(size_t)(c*16 + hh)*S_ + qt2*128 + w*16 + ln16] = lse;
}

// ---------------------------------------------------------------------------
// combine: blend 2 chunk partials, 16 heads.  grid 2048 x 256 thr.
// ---------------------------------------------------------------------------
__global__ __launch_bounds__(256) void combine(const u16* __restrict__ opart,
                                               const float* __restrict__ ml,
                                               u16* __restrict__ ctx) {
    int t = blockIdx.x * 256 + threadIdx.x;
    int qh = t >> 4;
    int q = qh >> 4, hh = qh & 15;
    int dv0 = (t & 15) * 8;

    float ls0 = ml[(size_t)hh * S_ + q];
    float ls1 = ml[(size_t)(16 + hh) * S_ + q];
    float m = fmaxf(ls0, ls1);
    float e0 = __expf(ls0 - m), e1 = __expf(ls1 - m);
    float is = 1.0f / (e0 + e1);

    u16x8 a = *reinterpret_cast<const u16x8*>(&opart[((size_t)hh*S_ + q)*128 + dv0]);
    u16x8 b = *reinterpret_cast<const u16x8*>(&opart[((size_t)(16 + hh)*S_ + q)*128 + dv0]);
    u16x8 o;
#pragma unroll
    for (int j = 0; j < 8; ++j)
        o[j] = f2bf((e0 * bf2f(a[j]) + e1 * bf2f(b[j])) * is);
    *reinterpret_cast<u16x8*>(&ctx[(size_t)q * D_ + hh * DH_ + dv0]) = o;
}

// ---------------------------------------------------------------------------
// r22 orchestration == r21 (proven memory plan); flash is 2-phase pipelined.
// ---------------------------------------------------------------------------
extern "C" void kernel_launch(void* const* d_in, const int* in_sizes, int n_in,
                              void* d_out, int out_size, void* d_ws, size_t ws_size,
                              hipStream_t stream) {
    const float* x    = (const float*)d_in[0];
    const float* Wq   = (const float*)d_in[1];
    const float* Wdkv = (const float*)d_in[2];
    const float* Wuk  = (const float*)d_in[3];
    const float* Wuv  = (const float*)d_in[4];
    const float* Wo   = (const float*)d_in[5];
    const float* lnw  = (const float*)d_in[6];
    const float* lnb  = (const float*)d_in[7];

    float* out = (float*)d_out;
    float* ckv = out + (size_t)M_ * D_;               // (M,L) real output

    char* ws = (char*)d_ws;
    u16*   xb_bf   = (u16*)(ws);                      // S0 (16 MiB)
    u16*   kmat    = (u16*)(ws);                      //   reuse after xb dead
    u16*   qb_bf   = (u16*)(ws + (size_t)16777216);   // S1 full-M
    u16*   ctx_b1  = (u16*)(ws + (size_t)16777216);   //   qb_b0 half, after b0
    u16*   vb_bf   = (u16*)(ws + (size_t)33554432);   // S2 per batch
    u16*   wo_bf   = (u16*)(ws + (size_t)33554432);   //   reuse after flash(b)
    u16*   ckv_bf  = (u16*)(ws + (size_t)41943040);   // S3 full-M (4 MiB)
    u16*   wuv_bf  = (u16*)(ws + (size_t)46137344);   // S4 (2 MiB)
    float* ml      = (float*)(ws + (size_t)48234496); // S5 (256 KiB)

    char*  ob0     = (char*)d_out;                    // out_b0 region (16 MiB)
    u16*   wslot   = (u16*)ob0;                       // phase-A weight slot
    float* ckvp    = (float*)(ob0 + 8388608);         // phase-A f32 scratch
    u16*   ctx_b0  = (u16*)(out + (size_t)S_ * D_);   // out_b1 head (8 MiB)

    dim3 blk(256);

    // ---- Phase A (batch-fused projections) ----
    cvt_bf16<<<dim3(8192), blk, 0, stream>>>(x, xb_bf);
    cvt_bf16<<<dim3(1024), blk, 0, stream>>>(Wdkv, wslot);
    mgemm<float,64,64,2,2><<<dim3(L_/64, M_/64), blk, 0, stream>>>(xb_bf, wslot, ckvp, L_, D_);
    ln_kernel<<<dim3(M_), blk, 0, stream>>>(ckvp, lnw, lnb, ckv);
    cvt_bf16<<<dim3(2048), blk, 0, stream>>>(ckv, ckv_bf);
    cvt_bf16<<<dim3(4096), blk, 0, stream>>>(Wq, wslot);
    mgemm<u16,128,128,2,2><<<dim3(D_/128, M_/128), blk, 0, stream>>>(xb_bf, wslot, qb_bf, D_, D_);
    cvt_bf16<<<dim3(1024), blk, 0, stream>>>(Wuv, wuv_bf);
    // k materialization: kmat = ckv @ Wuk^T  (full M)
    cvt_bf16<<<dim3(1024), blk, 0, stream>>>(Wuk, wslot);
    mgemm<u16,128,64,4,1><<<dim3(D_/64, M_/128), blk, 0, stream>>>(ckv_bf, wslot, kmat, D_, L_);

    // ---- Per-batch attention + output projection ----
    for (int b = 0; b < B_; ++b) {
        const u16* qb_b    = qb_bf  + (size_t)b * S_ * D_;
        const u16* kmat_b  = kmat   + (size_t)b * S_ * D_;
        const u16* ckvbf_b = ckv_bf + (size_t)b * S_ * L_;
        float*     outb    = out    + (size_t)b * S_ * D_;
        u16*       opart   = (u16*)outb;                       // 16 MiB
        u16*       ctx_b   = (b == 0) ? ctx_b0 : ctx_b1;

        // v_b = ckv_b @ Wuv^T
        mgemm<u16,128,64,4,1><<<dim3(D_/64, S_/128), blk, 0, stream>>>(ckvbf_b, wuv_bf, vb_bf, D_, L_);

        // fused 16-head flash + combine
        flash_split<<<dim3(16, 16, 2), dim3(512), 0, stream>>>(
            qb_b, kmat_b, vb_bf, opart, ml);
        combine<<<dim3(2048), blk, 0, stream>>>(opart, ml, ctx_b);

        // Wo -> bf16 into dead vb slot, then out_b = ctx_b @ Wo^T
        cvt_bf16<<<dim3(4096), blk, 0, stream>>>(Wo, wo_bf);
        mgemm<float,128,64,4,1><<<dim3(D_/64, S_/128), blk, 0, stream>>>(ctx_b, wo_bf, outb, D_, D_);
    }
}